// Round 5
// baseline (214.145 us; speedup 1.0000x reference)
//
#include <hip/hip_runtime.h>

// YOLO-v1-style loss, exact port of the JAX reference.
// S=7, B=2, C=20, channels per cell = 30 (120 B):
//   ch 0..19 class, ch 20..24 box0 xywhc, ch 25..29 box1 xywhc.
// Loss only touches channels 10..29 (cls uses [5*B:]=10.. — reference quirk).
//
// R5: persistent, barrier-free, software-pipelined.
//  - wave-private LDS transpose tiles (DS ops of one wave are ordered -> no
//    __syncthreads in the loop; R4's 3 barriers coupled waves and ate the
//    coalescing win).
//  - grid-stride over 64-cell tiles, 2-deep register pipeline: next tile's
//    20 coalesced float2 loads are in flight during current tile's compute.
//  - 784 blocks (~3/CU resident), 784 atomics.

#define CH       30
#define EPSL     1e-6f
#define TPB      256
#define WAVES    (TPB / 64)
#define CSTRIDE  22                      // dwords per cell in LDS (20 live + 2 pad)
#define WTILE    (64 * CSTRIDE)          // dwords per wave tile (1408) = 5632 B

__device__ __forceinline__ float sgnf(float x) {
    return (x > 0.0f) ? 1.0f : ((x < 0.0f) ? -1.0f : 0.0f);
}

// coalesced load of one 64-cell tile's live regions (both tensors)
__device__ __forceinline__ void load_tile(const char* pb, const char* ab,
                                          const int* offs, const int* cc, int nc,
                                          float2* rp, float2* ra) {
#pragma unroll
    for (int k = 0; k < 10; ++k)
        if (cc[k] < nc) rp[k] = *(const float2*)(pb + offs[k]);
#pragma unroll
    for (int k = 0; k < 10; ++k)
        if (cc[k] < nc) ra[k] = *(const float2*)(ab + offs[k]);
}

// wave-private LDS transpose + per-cell loss; returns this lane's contribution
__device__ __forceinline__ float compute_tile(float* wbuf, int lane,
                                              const int* cc, const int* ss, int nc,
                                              const float2* rp, const float2* ra) {
    // scatter p then a into disjoint halves?  No - single buffer reused is
    // UNSAFE pipelined (next scatter vs this gather is fine in-order, but p
    // and a must coexist).  Use both halves: p at [0], a at [WTILE/2]... the
    // tile is 64*22 dwords; keep p in even slots layout: simplest = two
    // regions of 64*11 dwords?  CSTRIDE must stay >=20.  Instead: p region
    // [0 .. 64*22) is shared: p uses dwords [c*22 + 2s], a uses a second
    // buffer offset passed in by caller via wbuf pointer arithmetic.
    // (caller hands a 2*WTILE region: p at wbuf, a at wbuf+WTILE)
    float* pbuf = wbuf;
    float* abuf = wbuf + WTILE;
#pragma unroll
    for (int k = 0; k < 10; ++k)
        if (cc[k] < nc) *(float2*)&pbuf[cc[k] * CSTRIDE + 2 * ss[k]] = rp[k];
#pragma unroll
    for (int k = 0; k < 10; ++k)
        if (cc[k] < nc) *(float2*)&abuf[cc[k] * CSTRIDE + 2 * ss[k]] = ra[k];

    float pd[20], ad[20];
#pragma unroll
    for (int s = 0; s < 10; ++s) {
        const float2 v = *(const float2*)&pbuf[lane * CSTRIDE + 2 * s];
        pd[2 * s] = v.x; pd[2 * s + 1] = v.y;
    }
#pragma unroll
    for (int s = 0; s < 10; ++s) {
        const float2 v = *(const float2*)&abuf[lane * CSTRIDE + 2 * s];
        ad[2 * s] = v.x; ad[2 * s + 1] = v.y;
    }

    float lsum = 0.0f;
    if (lane < nc) {
        float pxv[2], pyv[2], pwv[2], phv[2], pcv[2];
        float axv[2], ayv[2], awv[2], ahv[2];
#pragma unroll
        for (int b = 0; b < 2; ++b) {
            pxv[b] = pd[10 + 5 * b]; pyv[b] = pd[11 + 5 * b];
            pwv[b] = pd[12 + 5 * b]; phv[b] = pd[13 + 5 * b];
            pcv[b] = pd[14 + 5 * b];
            axv[b] = ad[10 + 5 * b]; ayv[b] = ad[11 + 5 * b];
            awv[b] = ad[12 + 5 * b]; ahv[b] = ad[13 + 5 * b];
        }
        const bool obj = ad[14] > 0.0f;   // a's box-0 conf (channel 24)

        float miou[2];
#pragma unroll
        for (int pb2 = 0; pb2 < 2; ++pb2) {
            const float p_tlx = pxv[pb2] - 0.5f * pwv[pb2];
            const float p_tly = pyv[pb2] - 0.5f * phv[pb2];
            const float p_brx = pxv[pb2] + 0.5f * pwv[pb2];
            const float p_bry = pyv[pb2] + 0.5f * phv[pb2];
            const float p_area = pwv[pb2] * phv[pb2];
            float best = -3.4e38f;
#pragma unroll
            for (int ab2 = 0; ab2 < 2; ++ab2) {
                const float a_tlx = axv[ab2] - 0.5f * awv[ab2];
                const float a_tly = ayv[ab2] - 0.5f * ahv[ab2];
                const float a_brx = axv[ab2] + 0.5f * awv[ab2];
                const float a_bry = ayv[ab2] + 0.5f * ahv[ab2];
                float sx = fminf(p_brx, a_brx) - fmaxf(p_tlx, a_tlx);
                float sy = fminf(p_bry, a_bry) - fmaxf(p_tly, a_tly);
                sx = fmaxf(sx, 0.0f);
                sy = fmaxf(sy, 0.0f);
                const float inter = sx * sy;
                const float uni = p_area + awv[ab2] * ahv[ab2] - inter;
                const float iou = (uni == 0.0f) ? 0.0f : (inter / uni);
                best = fmaxf(best, iou);
            }
            miou[pb2] = best;
        }
        const int resp = (miou[1] > miou[0]) ? 1 : 0;   // jnp.argmax first-max

#pragma unroll
        for (int b = 0; b < 2; ++b) {
            const bool oij = obj && (b == resp);
            if (oij) {
                const float dx = axv[b] - pxv[b];
                const float dy = ayv[b] - pyv[b];
                const float dw = sgnf(awv[b]) * sqrtf(awv[b] + EPSL) - sgnf(pwv[b]) * sqrtf(pwv[b] + EPSL);
                const float dh = sgnf(ahv[b]) * sqrtf(ahv[b] + EPSL) - sgnf(phv[b]) * sqrtf(phv[b] + EPSL);
                const float dc = 1.0f - pcv[b];
                lsum += 5.0f * (dx * dx + dy * dy + dw * dw + dh * dh) + dc * dc;
            } else {
                lsum += 0.5f * pcv[b] * pcv[b];   // noobj: pc^2
            }
        }
        if (obj) {
#pragma unroll
            for (int k = 0; k < 20; ++k) {
                const float d = pd[k] - ad[k];
                lsum += d * d;
            }
        }
    }
    return lsum;
}

__global__ __launch_bounds__(TPB) void yolo_loss_kernel(const float* __restrict__ p,
                                                        const float* __restrict__ a,
                                                        float* __restrict__ out,
                                                        long long n_cells) {
    // 2*WTILE dwords (p+a regions) per wave: 4 waves * 11264 B = 45 KB
    __shared__ __align__(16) float sbuf[WAVES * 2 * WTILE];
    __shared__ float wsum[WAVES];

    const int tid  = threadIdx.x;
    const int wave = tid >> 6;
    const int lane = tid & 63;
    float* wbuf = &sbuf[wave * 2 * WTILE];

    // lane's float2 slots: i = lane + 64k -> cell c=i/10, slot s=i%10,
    // byte offset within tile = c*120 + 40 + 8s (channels 10+2s, 11+2s)
    int cc[10], ss[10], offs[10];
#pragma unroll
    for (int k = 0; k < 10; ++k) {
        const int i = lane + 64 * k;
        const int c = i / 10;
        const int s = i - 10 * c;
        cc[k] = c; ss[k] = s;
        offs[k] = c * 120 + 40 + 8 * s;
    }

    const long long n_tiles = (n_cells + 63) >> 6;
    const long long gwave   = (long long)blockIdx.x * WAVES + wave;
    const long long stride  = (long long)gridDim.x * WAVES;

    float lsum = 0.0f;

    // ---- software-pipelined grid-stride over tiles (no barriers) ----
    long long t0 = gwave;
    float2 rpA[10], raA[10], rpB[10], raB[10];

    if (t0 < n_tiles) {
        int ncA = (int)min((long long)64, n_cells - t0 * 64);
        load_tile((const char*)p + t0 * 7680LL, (const char*)a + t0 * 7680LL,
                  offs, cc, ncA, rpA, raA);
        for (;;) {
            const long long t1 = t0 + stride;
            const bool have1 = t1 < n_tiles;
            int ncB = 0;
            if (have1) {
                ncB = (int)min((long long)64, n_cells - t1 * 64);
                load_tile((const char*)p + t1 * 7680LL, (const char*)a + t1 * 7680LL,
                          offs, cc, ncB, rpB, raB);
            }
            lsum += compute_tile(wbuf, lane, cc, ss, ncA, rpA, raA);
            if (!have1) break;

            const long long t2 = t1 + stride;
            const bool have2 = t2 < n_tiles;
            if (have2) {
                ncA = (int)min((long long)64, n_cells - t2 * 64);
                load_tile((const char*)p + t2 * 7680LL, (const char*)a + t2 * 7680LL,
                          offs, cc, ncA, rpA, raA);
            }
            lsum += compute_tile(wbuf, lane, cc, ss, ncB, rpB, raB);
            if (!have2) break;
            t0 = t2;
        }
    }

    // ---- reduction: wave shfl -> LDS -> one atomic per block ----
    float v = lsum;
#pragma unroll
    for (int off = 32; off > 0; off >>= 1)
        v += __shfl_down(v, off, 64);
    if (lane == 0) wsum[wave] = v;
    __syncthreads();
    if (tid == 0) {
        float t = 0.0f;
#pragma unroll
        for (int w = 0; w < WAVES; ++w) t += wsum[w];
        atomicAdd(out, t);
    }
}

extern "C" void kernel_launch(void* const* d_in, const int* in_sizes, int n_in,
                              void* d_out, int out_size, void* d_ws, size_t ws_size,
                              hipStream_t stream) {
    const float* p = (const float*)d_in[0];
    const float* a = (const float*)d_in[1];
    float* out = (float*)d_out;

    const long long n_cells = (long long)in_sizes[0] / CH;   // 16384*7*7 = 802816
    // n_tiles = 12544; 784 blocks * 4 waves = 3136 waves -> exactly 4 tiles/wave
    const int grid = 784;

    // d_out is re-poisoned (0xAA) before every timed replay -> must zero it here.
    hipMemsetAsync(d_out, 0, sizeof(float), stream);
    yolo_loss_kernel<<<grid, TPB, 0, stream>>>(p, a, out, n_cells);
}

// Round 6
// 207.396 us; speedup vs baseline: 1.0325x; 1.0325x over previous
//
#include <hip/hip_runtime.h>

// YOLO-v1-style loss, exact port of the JAX reference.
// S=7, B=2, C=20, channels per cell = 30 (120 B):
//   ch 0..19 class, ch 20..24 box0 xywhc, ch 25..29 box1 xywhc.
// Loss only touches channels 10..29 (cls uses [5*B:]=10.. — reference quirk).
//
// R6: coalesced + barrier-free + high occupancy (fixes R5's occupancy fail).
//  - coalesced float2 loads of the live 80 B regions, both tensors issued
//    up-front (40 wave-insts in flight).
//  - ONE wave-private LDS region per wave reused p-then-a (DS ops of a wave
//    execute in order -> no __syncthreads; 22.5 KB/block -> 7-block LDS cap).
//  - grid-stride, 2 tiles/wave (grid=1568), ~6 blocks/CU resident.

#define CH       30
#define EPSL     1e-6f
#define TPB      256
#define WAVES    (TPB / 64)
#define CSTRIDE  22                      // dwords per cell in LDS (20 live + 2 pad)
#define WTILE    (64 * CSTRIDE)          // 1408 dwords = 5632 B per wave

__device__ __forceinline__ float sgnf(float x) {
    return (x > 0.0f) ? 1.0f : ((x < 0.0f) ? -1.0f : 0.0f);
}

__global__ __launch_bounds__(TPB) void yolo_loss_kernel(const float* __restrict__ p,
                                                        const float* __restrict__ a,
                                                        float* __restrict__ out,
                                                        long long n_cells) {
    __shared__ __align__(16) float sbuf[WAVES * WTILE];   // 22528 B
    __shared__ float wsum[WAVES];

    const int tid  = threadIdx.x;
    const int wave = tid >> 6;
    const int lane = tid & 63;
    float* wbuf = &sbuf[wave * WTILE];

    // lane's float2 slots: i = lane + 64k -> cell c=i/10, slot s=i%10,
    // byte offset within a 64-cell tile = c*120 + 40 + 8s (channels 10+2s, 11+2s)
    int cc[10], ss[10], offs[10];
#pragma unroll
    for (int k = 0; k < 10; ++k) {
        const int i = lane + 64 * k;
        const int c = i / 10;
        const int s = i - 10 * c;
        cc[k] = c; ss[k] = s;
        offs[k] = c * 120 + 40 + 8 * s;
    }

    const long long n_tiles = (n_cells + 63) >> 6;           // 12544 (exact: 64*12544)
    const long long stride  = (long long)gridDim.x * WAVES;

    float lsum = 0.0f;

    for (long long t = (long long)blockIdx.x * WAVES + wave; t < n_tiles; t += stride) {
        const char* pb = (const char*)p + t * 7680LL;
        const char* ab = (const char*)a + t * 7680LL;
        const int nc = (int)min((long long)64, n_cells - t * 64);

        // ---- both tensors' coalesced loads issued up-front (max MLP) ----
        float2 rp[10], ra[10];
#pragma unroll
        for (int k = 0; k < 10; ++k)
            if (cc[k] < nc) rp[k] = *(const float2*)(pb + offs[k]);
#pragma unroll
        for (int k = 0; k < 10; ++k)
            if (cc[k] < nc) ra[k] = *(const float2*)(ab + offs[k]);

        // ---- wave-private transpose: p through LDS, then a (no barriers) ----
        float pd[20], ad[20];
#pragma unroll
        for (int k = 0; k < 10; ++k)
            if (cc[k] < nc) *(float2*)&wbuf[cc[k] * CSTRIDE + 2 * ss[k]] = rp[k];
#pragma unroll
        for (int s = 0; s < 10; ++s) {
            const float2 v = *(const float2*)&wbuf[lane * CSTRIDE + 2 * s];
            pd[2 * s] = v.x; pd[2 * s + 1] = v.y;
        }
#pragma unroll
        for (int k = 0; k < 10; ++k)
            if (cc[k] < nc) *(float2*)&wbuf[cc[k] * CSTRIDE + 2 * ss[k]] = ra[k];
#pragma unroll
        for (int s = 0; s < 10; ++s) {
            const float2 v = *(const float2*)&wbuf[lane * CSTRIDE + 2 * s];
            ad[2 * s] = v.x; ad[2 * s + 1] = v.y;
        }

        // ---- per-cell loss (pd[j]/ad[j] = channel 10+j) ----
        if (lane < nc) {
            float pxv[2], pyv[2], pwv[2], phv[2], pcv[2];
            float axv[2], ayv[2], awv[2], ahv[2];
#pragma unroll
            for (int b = 0; b < 2; ++b) {
                pxv[b] = pd[10 + 5 * b]; pyv[b] = pd[11 + 5 * b];
                pwv[b] = pd[12 + 5 * b]; phv[b] = pd[13 + 5 * b];
                pcv[b] = pd[14 + 5 * b];
                axv[b] = ad[10 + 5 * b]; ayv[b] = ad[11 + 5 * b];
                awv[b] = ad[12 + 5 * b]; ahv[b] = ad[13 + 5 * b];
            }
            const bool obj = ad[14] > 0.0f;   // a's box-0 conf (channel 24)

            float miou[2];
#pragma unroll
            for (int pb2 = 0; pb2 < 2; ++pb2) {
                const float p_tlx = pxv[pb2] - 0.5f * pwv[pb2];
                const float p_tly = pyv[pb2] - 0.5f * phv[pb2];
                const float p_brx = pxv[pb2] + 0.5f * pwv[pb2];
                const float p_bry = pyv[pb2] + 0.5f * phv[pb2];
                const float p_area = pwv[pb2] * phv[pb2];
                float best = -3.4e38f;
#pragma unroll
                for (int ab2 = 0; ab2 < 2; ++ab2) {
                    const float a_tlx = axv[ab2] - 0.5f * awv[ab2];
                    const float a_tly = ayv[ab2] - 0.5f * ahv[ab2];
                    const float a_brx = axv[ab2] + 0.5f * awv[ab2];
                    const float a_bry = ayv[ab2] + 0.5f * ahv[ab2];
                    float sx = fminf(p_brx, a_brx) - fmaxf(p_tlx, a_tlx);
                    float sy = fminf(p_bry, a_bry) - fmaxf(p_tly, a_tly);
                    sx = fmaxf(sx, 0.0f);
                    sy = fmaxf(sy, 0.0f);
                    const float inter = sx * sy;
                    const float uni = p_area + awv[ab2] * ahv[ab2] - inter;
                    const float iou = (uni == 0.0f) ? 0.0f : (inter / uni);
                    best = fmaxf(best, iou);
                }
                miou[pb2] = best;
            }
            const int resp = (miou[1] > miou[0]) ? 1 : 0;   // jnp.argmax first-max

#pragma unroll
            for (int b = 0; b < 2; ++b) {
                const bool oij = obj && (b == resp);
                if (oij) {
                    const float dx = axv[b] - pxv[b];
                    const float dy = ayv[b] - pyv[b];
                    const float dw = sgnf(awv[b]) * sqrtf(awv[b] + EPSL) - sgnf(pwv[b]) * sqrtf(pwv[b] + EPSL);
                    const float dh = sgnf(ahv[b]) * sqrtf(ahv[b] + EPSL) - sgnf(phv[b]) * sqrtf(phv[b] + EPSL);
                    const float dc = 1.0f - pcv[b];
                    lsum += 5.0f * (dx * dx + dy * dy + dw * dw + dh * dh) + dc * dc;
                } else {
                    lsum += 0.5f * pcv[b] * pcv[b];   // noobj: pc^2
                }
            }
            if (obj) {
#pragma unroll
                for (int k = 0; k < 20; ++k) {
                    const float d = pd[k] - ad[k];
                    lsum += d * d;
                }
            }
        }
    }

    // ---- reduction: wave shfl -> LDS -> one atomic per block ----
    float v = lsum;
#pragma unroll
    for (int off = 32; off > 0; off >>= 1)
        v += __shfl_down(v, off, 64);
    if (lane == 0) wsum[wave] = v;
    __syncthreads();
    if (tid == 0) {
        float t = 0.0f;
#pragma unroll
        for (int w = 0; w < WAVES; ++w) t += wsum[w];
        atomicAdd(out, t);
    }
}

extern "C" void kernel_launch(void* const* d_in, const int* in_sizes, int n_in,
                              void* d_out, int out_size, void* d_ws, size_t ws_size,
                              hipStream_t stream) {
    const float* p = (const float*)d_in[0];
    const float* a = (const float*)d_in[1];
    float* out = (float*)d_out;

    const long long n_cells = (long long)in_sizes[0] / CH;   // 16384*7*7 = 802816
    // n_tiles = 12544; 1568 blocks * 4 waves = 6272 waves -> exactly 2 tiles/wave
    const int grid = 1568;

    // d_out is re-poisoned (0xAA) before every timed replay -> must zero it here.
    hipMemsetAsync(d_out, 0, sizeof(float), stream);
    yolo_loss_kernel<<<grid, TPB, 0, stream>>>(p, a, out, n_cells);
}